// Round 1
// baseline (163.048 us; speedup 1.0000x reference)
//
#include <hip/hip_runtime.h>
#include <math.h>

#define N_NODES 100000
#define N_EDGES 1600000

// out is poisoned 0xAA before every timed launch — must zero it ourselves.
__global__ void zero_kernel(float* __restrict__ out, int n) {
    int i = blockIdx.x * blockDim.x + threadIdx.x;
    if (i < n) out[i] = 0.0f;
}

__global__ __launch_bounds__(256) void edge_kernel(
    const float* __restrict__ pos,        // [N_NODES,3]
    const float* __restrict__ node_feats, // [N_NODES,9]
    const float* __restrict__ W1,         // [10,16]
    const float* __restrict__ W2,         // [16,3]
    const int*   __restrict__ edge_src,   // [N_EDGES]
    const int*   __restrict__ edge_dst,   // [N_EDGES]
    float* __restrict__ out)              // [N_NODES]
{
    // W1 staged with row stride 17 to break LDS bank aliasing on per-lane row reads.
    __shared__ float sW1[10 * 17];
    __shared__ float sW2[16 * 3];
    const int t = threadIdx.x;
    if (t < 160) sW1[(t >> 4) * 17 + (t & 15)] = W1[t];
    if (t < 48)  sW2[t] = W2[t];
    __syncthreads();

    const int e = blockIdx.x * blockDim.x + t;
    if (e >= N_EDGES) return;

    const int src = edge_src[e];
    const int dst = edge_dst[e];

    // edge vector = pos[dst] - pos[src]  (pos table is 1.2 MB -> L2 hit)
    const float* ps = pos + 3 * src;
    const float* pd = pos + 3 * dst;
    const float vx = pd[0] - ps[0];
    const float vy = pd[1] - ps[1];
    const float vz = pd[2] - ps[2];

    const float r    = sqrtf(vx * vx + vy * vy + vz * vz);
    const float inv  = 1.0f / (r + 1e-12f);
    const float x = vx * inv, y = vy * inv, z = vz * inv;

    // spherical harmonics lmax=2 (sh0 == 1 folded into path_s)
    const float s3  = 1.7320508075688772f;
    const float s5  = 2.23606797749979f;
    const float s15 = 3.872983346207417f;
    const float sh1 = s3 * x;
    const float sh2 = s3 * y;
    const float sh3 = s3 * z;
    const float sh4 = s15 * x * z;
    const float sh5 = s15 * x * y;
    const float sh6 = s5 * (y * y - 0.5f * (x * x + z * z));
    const float sh7 = s15 * y * z;
    const float sh8 = 0.5f * s15 * (z * z - x * x);

    // radial basis: vals[i] = (i+1)*step, step = 5/11; d_i = r/step - (i+1).
    // |d_i| < 1 holds for at most bins floor(q)-1 and floor(q), q = r/step.
    const float q = r * 2.2f;                 // 11/5
    const int   k = (int)floorf(q);
    int   b0 = k - 1, b1 = k;
    float d0 = q - (float)k;                  // in [0,1)
    float d1 = d0 - 1.0f;                     // in [-1,0)
    const float A = 8.43357307f;              // 1.14136 * e^2
    float e0 = 0.0f, e1 = 0.0f;
    if (b0 >= 0 && b0 < 10) {
        float dd = d0 * d0;
        if (dd < 1.0f) e0 = A * expf(-1.0f / (1.0f - dd));
    }
    if (b1 >= 0 && b1 < 10) {
        float dd = d1 * d1;
        if (dd < 1.0f) e1 = A * expf(-1.0f / (1.0f - dd));
    }
    b0 = (b0 >= 0 && b0 < 10) ? b0 : 0;       // e0 already zeroed if OOR
    b1 = (b1 >= 0 && b1 < 10) ? b1 : 0;

    // h = relu(basis @ W1); w = h @ W2   (all positive scales folded into FINAL)
    const float* w1r0 = sW1 + b0 * 17;
    const float* w1r1 = sW1 + b1 * 17;
    float acc0 = 0.0f, acc1 = 0.0f, acc2 = 0.0f;
#pragma unroll
    for (int j = 0; j < 16; ++j) {
        const float hj = fmaxf(e0 * w1r0[j] + e1 * w1r1[j], 0.0f);
        acc0 = fmaf(hj, sW2[j * 3 + 0], acc0);
        acc1 = fmaf(hj, sW2[j * 3 + 1], acc1);
        acc2 = fmaf(hj, sW2[j * 3 + 2], acc2);
    }

    // node_feats gather (3.6 MB table -> L2)
    const float* xf = node_feats + 9 * src;
    const float path_s = xf[0];
    const float path_p = (xf[1] * sh1 + xf[2] * sh2 + xf[3] * sh3) * 0.5773502691896258f; // /sqrt(3)
    const float path_d = (xf[4] * sh4 + xf[5] * sh5 + xf[6] * sh6
                        + xf[7] * sh7 + xf[8] * sh8) * 0.4472135954999579f;               // /sqrt(5)

    // FINAL = sqrt(2) / (4 * sqrt(3) * sqrt(10)) = 1/(4*sqrt(15))
    const float FINAL = 0.06454972243679028f;
    const float msg = (acc0 * path_s + acc1 * path_p + acc2 * path_d) * FINAL;

    unsafeAtomicAdd(out + dst, msg);   // native global_atomic_add_f32
}

extern "C" void kernel_launch(void* const* d_in, const int* in_sizes, int n_in,
                              void* d_out, int out_size, void* d_ws, size_t ws_size,
                              hipStream_t stream) {
    const float* pos        = (const float*)d_in[0];
    const float* node_feats = (const float*)d_in[1];
    const float* W1         = (const float*)d_in[2];
    const float* W2         = (const float*)d_in[3];
    const int*   edge_src   = (const int*)d_in[4];
    const int*   edge_dst   = (const int*)d_in[5];
    float* out = (float*)d_out;

    zero_kernel<<<(N_NODES + 255) / 256, 256, 0, stream>>>(out, N_NODES);
    edge_kernel<<<(N_EDGES + 255) / 256, 256, 0, stream>>>(
        pos, node_feats, W1, W2, edge_src, edge_dst, out);
}